// Round 3
// baseline (558.224 us; speedup 1.0000x reference)
//
#include <hip/hip_runtime.h>
#include <stdint.h>

// Powderworld BehaviorFluidFlow: B=16, C=20, H=512, W=512, fp32.
// Two fall passes reduce to a composed gather along W:
//   out[c][x] = world[c][ s1[s2[x]] ]  for all 20 channels,
// with channel 6 overridden by positional new_fluid_momentum where the final
// cell id is a fluid. Decisions use only channels 0,1,2,6,8 + rand_movement.
//
// v3: ALL input staging via global_load_lds width=16 (42x 1KB chunks issued
// up-front by 8 waves -> max MLP, no VGPR round-trip); ALL stores float4
// (5 per thread vs 20 scalar dwords); barriers 10 -> 5.

#define WW 512
#define HH 512
#define CC 20
#define BB 16

__device__ __forceinline__ void gload_lds16(const float* g, float* l) {
    // width must be a literal; LDS dest is wave-uniform base + lane*16 (HW).
    __builtin_amdgcn_global_load_lds((__attribute__((address_space(1))) void*)(g),
                                     (__attribute__((address_space(3))) void*)(l),
                                     16, 0, 0);
}

__device__ __forceinline__ bool is_fluid_id(float id) {
    // empty=0, water=3, gas=9, lava=8, acid=12, agentKangaroo=14, agentLemming=15
    return (id == 0.0f) | (id == 3.0f) | (id == 9.0f) | (id == 8.0f) |
           (id == 12.0f) | (id == 14.0f) | (id == 15.0f);
}

__global__ __launch_bounds__(512)
void fluid_flow_kernel(const float* __restrict__ world,
                       const float* __restrict__ rand_movement,
                       float* __restrict__ out) {
    __shared__ __attribute__((aligned(16))) float id_s[WW];
    __shared__ __attribute__((aligned(16))) float den_s[WW];
    __shared__ __attribute__((aligned(16))) float grav_s[WW];
    __shared__ __attribute__((aligned(16))) float mom_s[WW];
    __shared__ __attribute__((aligned(16))) float didg_s[WW];
    __shared__ __attribute__((aligned(16))) float rm_s[WW];
    __shared__ __attribute__((aligned(16))) float momout_s[WW];
    __shared__ __attribute__((aligned(16))) float chbuf[15][WW];   // streamed channels
    __shared__ int   dbl_s[WW];
    __shared__ int   s1_s[WW];
    __shared__ __attribute__((aligned(16))) short sfin_s[WW];

    const int row  = blockIdx.x;           // 0 .. B*H-1
    const int b    = row >> 9;
    const int h    = row & (HH - 1);
    const int x    = threadIdx.x;          // 0 .. 511
    const int lane = x & 63;
    const int wv   = x >> 6;               // wave 0..7

    const size_t plane   = (size_t)HH * WW;
    const size_t baseRow = ((size_t)b * CC * HH + (size_t)h) * WW;
    const size_t rrow    = ((size_t)b * HH + (size_t)h) * WW;

    // ---- issue ALL global->LDS DMA: 42 chunks x 1KB (64 lanes x 16B) ----
    // k < 12: decision arrays (6 arrays x 2 halves); k >= 12: chbuf channels.
    for (int k = wv; k < 42; k += 8) {                 // k wave-uniform
        const float* gsrc;
        float*       ldst;
        if (k < 12) {
            const int a   = k >> 1;                    // array 0..5
            const int off = (k & 1) * 256;             // half-row offset (floats)
            switch (a) {
                case 0:  gsrc = world + baseRow + off;             ldst = id_s   + off; break;
                case 1:  gsrc = world + baseRow + plane + off;     ldst = den_s  + off; break;
                case 2:  gsrc = world + baseRow + 2 * plane + off; ldst = grav_s + off; break;
                case 3:  gsrc = world + baseRow + 6 * plane + off; ldst = mom_s  + off; break;
                case 4:  gsrc = world + baseRow + 8 * plane + off; ldst = didg_s + off; break;
                default: gsrc = rand_movement + rrow + off;        ldst = rm_s   + off; break;
            }
        } else {
            const int kk   = k - 12;
            const int ci   = kk >> 1;                  // chbuf slot 0..14
            const int off  = (kk & 1) * 256;
            const int ach  = ci + 3 + (ci >= 3) + (ci >= 4);  // {3,4,5,7,9..19}
            gsrc = world + baseRow + (size_t)ach * plane + off;
            ldst = &chbuf[ci][off];
        }
        gload_lds16(gsrc + lane * 4, ldst);
    }
    asm volatile("s_waitcnt vmcnt(0)" ::: "memory");   // DMA landed in LDS
    __syncthreads();                                   // B1

    // ---- pass 1 (fall_left = true): does_become_left ----
    {
        const float fd  = rm_s[x] + mom_s[x];          // + nfm(=0); matches (a+b)+c
        const bool matching = fd > 0.5f;               // fall_dir
        const float idc = id_s[x];
        const bool ia = (idc == 14.0f) | (idc == 15.0f);
        const bool ie = (idc == 0.0f) | (idc == 3.0f) | (idc == 9.0f) |
                        (idc == 8.0f) | (idc == 12.0f) | ia;
        const int  xl  = (x - 1) & (WW - 1);           // world_left = roll(shift=1)
        const bool ldl = (den_s[x] - den_s[xl]) > 0.0f;
        const bool ig  = grav_s[x]  == 1.0f;
        const bool ilg = grav_s[xl] == 1.0f;
        const bool ndg = (!(didg_s[x] > 0.0f)) | ia;
        dbl_s[x] = (matching & ie & ndg & ldl & ilg & ig) ? 1 : 0;
    }
    __syncthreads();                                   // B2

    // ---- pass-1 resolution: s1, momentum contribution ----
    float nfm;
    {
        const int d0 = dbl_s[x];
        const int d1 = dbl_s[(x + 1) & (WW - 1)];
        const int d2 = dbl_s[(x + 2) & (WW - 1)];
        const bool a1 = d0 && !d1;                     // take from left neighbor
        const bool b1 = d1 && !d2;                     // take from right neighbor
        s1_s[x] = a1 ? ((x - 1) & (WW - 1)) : (b1 ? ((x + 1) & (WW - 1)) : x);
        nfm = b1 ? 2.0f : 0.0f;
    }
    __syncthreads();                                   // B3 (guards s1 writes AND dbl reads)

    // ---- pass 2 (fall_left = false) on world1 = world0[s1] ----
    {
        const int c = s1_s[x];
        const int l = s1_s[(x + 1) & (WW - 1)];        // world_left = roll(shift=-1)
        const float fd = (rm_s[x] + mom_s[c]) + nfm;   // left-assoc like the ref
        const bool matching = !(fd > 0.5f);            // ~fall_dir
        const float idc = id_s[c];
        const bool ia = (idc == 14.0f) | (idc == 15.0f);
        const bool ie = (idc == 0.0f) | (idc == 3.0f) | (idc == 9.0f) |
                        (idc == 8.0f) | (idc == 12.0f) | ia;
        const bool ldl = (den_s[c] - den_s[l]) > 0.0f;
        const bool ig  = grav_s[c] == 1.0f;
        const bool ilg = grav_s[l] == 1.0f;
        const bool ndg = (!(didg_s[c] > 0.0f)) | ia;
        dbl_s[x] = (matching & ie & ndg & ldl & ilg & ig) ? 1 : 0;
    }
    __syncthreads();                                   // B4

    // ---- pass-2 resolution: composed source + final momentum ----
    {
        const int d0  = dbl_s[x];
        const int dm1 = dbl_s[(x - 1) & (WW - 1)];
        const int dm2 = dbl_s[(x - 2) & (WW - 1)];
        const bool a2 = d0  && !dm1;                   // take from x+1 of world1
        const bool b2 = dm1 && !dm2;                   // take from x-1 of world1
        const int s2  = a2 ? ((x + 1) & (WW - 1)) : (b2 ? ((x - 1) & (WW - 1)) : x);
        const int sx  = s1_s[s2];
        const float nfm_final = nfm + (b2 ? -2.0f : 0.0f);
        const bool fluid = is_fluid_id(id_s[sx]);
        momout_s[x] = fluid ? nfm_final : mom_s[sx];
        sfin_s[x]   = (short)sx;
    }
    __syncthreads();                                   // B5

    // ---- epilogue: gather + float4 stores, 5 channels per thread ----
    const int slot = x >> 7;                           // 0..3, wave-uniform
    const int q    = x & 127;                          // float4 index in row
    const short4 s4 = ((const short4*)sfin_s)[q];
    const int i0 = s4.x, i1 = s4.y, i2 = s4.z, i3 = s4.w;

    #pragma unroll
    for (int i = 0; i < 5; ++i) {
        const int c = slot + 4 * i;                    // wave-uniform channel
        float4 v;
        if (c == 6) {
            v = ((const float4*)momout_s)[q];          // identity-indexed
        } else {
            const float* src;
            if      (c == 0) src = id_s;
            else if (c == 1) src = den_s;
            else if (c == 2) src = grav_s;
            else if (c == 8) src = didg_s;
            else             src = chbuf[c - 3 - (c > 6) - (c > 8)];
            v.x = src[i0]; v.y = src[i1]; v.z = src[i2]; v.w = src[i3];
        }
        *(float4*)(out + baseRow + (size_t)c * plane + 4 * q) = v;
    }
}

extern "C" void kernel_launch(void* const* d_in, const int* in_sizes, int n_in,
                              void* d_out, int out_size, void* d_ws, size_t ws_size,
                              hipStream_t stream) {
    const float* world = (const float*)d_in[0];
    const float* rm    = (const float*)d_in[1];
    // d_in[2] (rand_interact) and d_in[3] (rand_element) are unused by the reference.
    float* out = (float*)d_out;

    dim3 grid(BB * HH);   // 8192 rows
    dim3 block(WW);       // 512 threads
    fluid_flow_kernel<<<grid, block, 0, stream>>>(world, rm, out);
}